// Round 1
// 839.568 us; speedup vs baseline: 1.0224x; 1.0224x over previous
//
#include <hip/hip_runtime.h>
#include <hip/hip_bf16.h>
#include <stdint.h>

// Cross-attention with q_len=1 per token, restructured low-rank:
//   qW[t,h,c]  = SCALE * x[t,:] @ (Wq_h @ Wk_h^T)      (K1, via precomputed WqkT from K0a)
//   dots[h,m]  = sum_c y[t,m,c] * qW[t,h,c]            (K2, MFMA 16x16x32 bf16)
//   attn       = softmax_m(dots)
//   ybar[h,c]  = sum_m attn[h,m] * y[t,m,c]            (K2, fp32 VALU)
//   result     = ybar @ (Wv_h @ Wout_h) + bout         (K3, via precomputed WvoT from K0b)
// K2 v2: token-per-wave (64-thr blocks, 4 blocks/CU, barrier-free). Removes the
// 4x-redundant dots MFMA/LDS reads and the 256-bpermute attn broadcast of the
// 4-wave version; LDS pipe drops from ~4600 to ~1200 cyc/CU-token -> HBM-bound.

typedef unsigned short u16;
typedef __attribute__((ext_vector_type(8))) short bf16x8;
typedef __attribute__((ext_vector_type(4))) float f32x4;
typedef __attribute__((ext_vector_type(4))) unsigned int u32x4;

#define NTOK 16384
#define SCALE_F 0.17677669529663687f

__device__ __forceinline__ u16 f2b(float v) {
  union { __hip_bfloat16 b; u16 s; } u;
  u.b = __float2bfloat16(v);
  return u.s;
}

__device__ __forceinline__ bf16x8 cvt8(f32x4 a, f32x4 b) {
  union { bf16x8 v; __hip_bfloat162 h[4]; } u;
  u.h[0] = __float22bfloat162_rn(float2{a[0], a[1]});
  u.h[1] = __float22bfloat162_rn(float2{a[2], a[3]});
  u.h[2] = __float22bfloat162_rn(float2{b[0], b[1]});
  u.h[3] = __float22bfloat162_rn(float2{b[2], b[3]});
  return u.v;
}

// async global->LDS, 16B per lane; LDS dest = wave-uniform base + lane*16
__device__ __forceinline__ void gll16(const float* g, const float* l) {
  __builtin_amdgcn_global_load_lds((const __attribute__((address_space(1))) void*)g,
                                   (__attribute__((address_space(3))) void*)l,
                                   16, 0, 0);
}

// ---------------- K0a: WqkT[j][e] = SCALE * sum_d Wq[e,h*32+d]*Wkv[c,h*32+d],  j = h*256+c
__global__ __launch_bounds__(256) void k0a(const float* __restrict__ Wq,
                                           const float* __restrict__ Wkv,
                                           u16* __restrict__ WqkT) {
  __shared__ float wq[16][260];
  __shared__ float wk[16][260];
  int tid = threadIdx.x;
  int e0 = blockIdx.x * 16, c0 = blockIdx.y * 16;
  {
    int r = tid >> 4, cs = (tid & 15) * 16;
#pragma unroll
    for (int i = 0; i < 4; i++) {
      *(f32x4*)&wq[r][cs + i * 4] = *(const f32x4*)(Wq + (e0 + r) * 256 + cs + i * 4);
      *(f32x4*)&wk[r][cs + i * 4] = *(const f32x4*)(Wkv + (c0 + r) * 512 + cs + i * 4);
    }
  }
  __syncthreads();
  int e = tid & 15, c = tid >> 4;
#pragma unroll
  for (int h = 0; h < 8; h++) {
    float acc = 0.f;
#pragma unroll
    for (int d = 0; d < 32; d++) acc += wq[e][h * 32 + d] * wk[c][h * 32 + d];
    WqkT[(h * 256 + c0 + c) * 256 + e0 + e] = f2b(acc * SCALE_F);
  }
}

// ---------------- K0b: WvoT[o][k] = sum_d Wkv[c,256+h*32+d]*Wout[h*32+d,o],  k = c*8+h
__global__ __launch_bounds__(256) void k0b(const float* __restrict__ Wkv,
                                           const float* __restrict__ Wout,
                                           u16* __restrict__ WvoT) {
  __shared__ float wv[16][260];
  __shared__ float wo[256][20];
  int tid = threadIdx.x;
  int o0 = blockIdx.x * 16, c0 = blockIdx.y * 16;
  {
    int r = tid >> 4, cs = (tid & 15) * 16;
#pragma unroll
    for (int i = 0; i < 4; i++)
      *(f32x4*)&wv[r][cs + i * 4] = *(const f32x4*)(Wkv + (c0 + r) * 512 + 256 + cs + i * 4);
#pragma unroll
    for (int i = 0; i < 4; i++)
      *(f32x4*)&wo[tid][i * 4] = *(const f32x4*)(Wout + tid * 256 + o0 + i * 4);
  }
  __syncthreads();
  int o = tid >> 4, c = tid & 15;
  union { u16 s[8]; u32x4 v; } pk;
#pragma unroll
  for (int h = 0; h < 8; h++) {
    float acc = 0.f;
#pragma unroll
    for (int d = 0; d < 32; d++) acc += wv[c][h * 32 + d] * wo[h * 32 + d][o];
    pk.s[h] = f2b(acc);
  }
  *(u32x4*)(WvoT + (o0 + o) * 2048 + (c0 + c) * 8) = pk.v;
}

// ---------------- K1: qW[t, h*256+c] = bf16(x) @ WqkT   (M=16384, N=2048, K=256)
__global__ __launch_bounds__(256) void k1(const float* __restrict__ X,
                                          const u16* __restrict__ WqkT,
                                          u16* __restrict__ qW) {
  __shared__ u16 As[128][72];
  __shared__ u16 Bs[128][72];
  int tid = threadIdx.x;
  int wave = tid >> 6, lane = tid & 63;
  int l15 = lane & 15, kg = lane >> 4;
  int m0 = blockIdx.x * 128, n0 = blockIdx.y * 128;
  int sr = tid >> 1, sk = (tid & 1) * 32;
  f32x4 acc[4][4] = {};
  for (int kc = 0; kc < 256; kc += 64) {
#pragma unroll
    for (int i = 0; i < 4; i++) {
      f32x4 a = *(const f32x4*)(X + (size_t)(m0 + sr) * 256 + kc + sk + i * 8);
      f32x4 b = *(const f32x4*)(X + (size_t)(m0 + sr) * 256 + kc + sk + i * 8 + 4);
      *(bf16x8*)&As[sr][sk + i * 8] = cvt8(a, b);
      *(u32x4*)&Bs[sr][sk + i * 8] = *(const u32x4*)(WqkT + (n0 + sr) * 256 + kc + sk + i * 8);
    }
    __syncthreads();
    int rb = (wave >> 1) * 64, cb = (wave & 1) * 64;
#pragma unroll
    for (int ks = 0; ks < 2; ks++) {
      bf16x8 af[4], bfm[4];
#pragma unroll
      for (int i = 0; i < 4; i++) af[i] = *(const bf16x8*)&As[rb + i * 16 + l15][ks * 32 + kg * 8];
#pragma unroll
      for (int i = 0; i < 4; i++) bfm[i] = *(const bf16x8*)&Bs[cb + i * 16 + l15][ks * 32 + kg * 8];
#pragma unroll
      for (int mt = 0; mt < 4; mt++)
#pragma unroll
        for (int nt = 0; nt < 4; nt++)
          acc[mt][nt] = __builtin_amdgcn_mfma_f32_16x16x32_bf16(af[mt], bfm[nt], acc[mt][nt], 0, 0, 0);
    }
    __syncthreads();
  }
  int rb = m0 + (wave >> 1) * 64, cb = n0 + (wave & 1) * 64;
  int q = lane >> 4;
#pragma unroll
  for (int mt = 0; mt < 4; mt++)
#pragma unroll
    for (int nt = 0; nt < 4; nt++)
#pragma unroll
      for (int r = 0; r < 4; r++)
        qW[(size_t)(rb + mt * 16 + q * 4 + r) * 2048 + cb + nt * 16 + l15] = f2b(acc[mt][nt][r]);
}

// ---------------- K2 v2: per-token attention, 1 wave = 1 token. 64-thr blocks,
// 1024 persistent blocks (4/CU), 16 tokens each, barrier-free, single swizzled buffer.
__global__ __launch_bounds__(64) void k2(const float* __restrict__ Y,
                                         const u16* __restrict__ qW,
                                         u16* __restrict__ ybar) {
  __shared__ float buf[32][256];    // 32 KiB, one token's y, XOR-swizzled 16B groups
  __shared__ float attn_s[32][8];   // 1 KiB broadcast scratch
  int lane = threadIdx.x;           // 0..63 (single wave)
  int l15 = lane & 15, kg = lane >> 4;
  int h8 = l15 & 7;
  int t0 = blockIdx.x * 16;

  // prologue: stage token t0 (async), preload its qW row
  {
    const float* g = Y + (size_t)t0 * 8192;
#pragma unroll
    for (int r = 0; r < 32; r++)
      gll16(g + r * 256 + ((lane ^ (r & 7)) << 2), &buf[r][0]);
  }
  bf16x8 bfr[8];
  {
    const u16* qwt = qW + ((size_t)t0 << 11) + h8 * 256 + kg * 8;
#pragma unroll
    for (int s = 0; s < 8; s++) bfr[s] = *(const bf16x8*)(qwt + s * 32);
  }

#pragma unroll 1
  for (int i = 0; i < 16; i++) {
    int t = t0 + i;
    // wait: staging of token t (global_load_lds) + qW prefetch complete
    asm volatile("s_waitcnt vmcnt(0)" ::: "memory");

    // ---- dots[m, h] via MFMA, computed ONCE (A = y rows, B = qW cols; cols 8-15 dup)
    f32x4 D[2] = {f32x4{0.f, 0.f, 0.f, 0.f}, f32x4{0.f, 0.f, 0.f, 0.f}};
#pragma unroll
    for (int s = 0; s < 8; s++) {
#pragma unroll
      for (int mt = 0; mt < 2; mt++) {
        int row = mt * 16 + l15;
        int g0 = s * 8 + kg * 2;
        f32x4 y0 = *(const f32x4*)&buf[row][((g0) ^ (row & 7)) << 2];
        f32x4 y1 = *(const f32x4*)&buf[row][((g0 + 1) ^ (row & 7)) << 2];
        D[mt] = __builtin_amdgcn_mfma_f32_16x16x32_bf16(cvt8(y0, y1), bfr[s], D[mt], 0, 0, 0);
      }
    }

    // prefetch qW for t+1 (bfr consumed by the MFMAs above; loads fly under softmax/PV)
    if (i + 1 < 16) {
      const u16* qn = qW + ((size_t)(t + 1) << 11) + h8 * 256 + kg * 8;
#pragma unroll
      for (int s = 0; s < 8; s++) bfr[s] = *(const bf16x8*)(qn + s * 32);
    }

    // ---- softmax over m (D-frag: col=h=l15, m = mt*16 + kg*4 + r)
    float mx = -1e30f;
#pragma unroll
    for (int mt = 0; mt < 2; mt++)
#pragma unroll
      for (int r = 0; r < 4; r++) mx = fmaxf(mx, D[mt][r]);
    mx = fmaxf(mx, __shfl_xor(mx, 16));
    mx = fmaxf(mx, __shfl_xor(mx, 32));
    float sum = 0.f;
    float at[2][4];
#pragma unroll
    for (int mt = 0; mt < 2; mt++)
#pragma unroll
      for (int r = 0; r < 4; r++) {
        float e = __expf(D[mt][r] - mx);
        at[mt][r] = e;
        sum += e;
      }
    sum += __shfl_xor(sum, 16);
    sum += __shfl_xor(sum, 32);
    float inv = 1.0f / sum;
#pragma unroll
    for (int mt = 0; mt < 2; mt++)
#pragma unroll
      for (int r = 0; r < 4; r++) at[mt][r] *= inv;

    // ---- attn -> LDS scratch (cols 0-7 only; per-wave DS is in-order, no barrier)
    if (l15 < 8) {
#pragma unroll
      for (int mt = 0; mt < 2; mt++)
#pragma unroll
        for (int r = 0; r < 4; r++)
          attn_s[mt * 16 + kg * 4 + r][l15] = at[mt][r];
    }

    // ---- PV: ybar[h][c] = sum_m attn[h][m]*y[m][c]; lane owns c = lane*4..+3, ALL 8 heads
    float acc[8][4] = {};
#pragma unroll
    for (int m = 0; m < 32; m++) {
      f32x4 yv = *(const f32x4*)&buf[m][(lane ^ (m & 7)) << 2];
      f32x4 a0 = *(const f32x4*)&attn_s[m][0];   // uniform-address broadcast
      f32x4 a1 = *(const f32x4*)&attn_s[m][4];
#pragma unroll
      for (int h = 0; h < 4; h++)
#pragma unroll
        for (int c = 0; c < 4; c++) {
          acc[h][c]     += a0[h] * yv[c];
          acc[h + 4][c] += a1[h] * yv[c];
        }
    }

    // all LDS reads of buf(t) retired before DMA overwrites it
    asm volatile("s_waitcnt lgkmcnt(0)" ::: "memory");

    // ---- stage token t+1 (async; overlaps store + next loop-top)
    if (i + 1 < 16) {
      const float* g = Y + (size_t)(t + 1) * 8192;
#pragma unroll
      for (int r = 0; r < 32; r++)
        gll16(g + r * 256 + ((lane ^ (r & 7)) << 2), &buf[r][0]);
    }

    // ---- store ybar(t) bf16, k = c*8 + h; lane writes 64 contiguous bytes
    u16* op = ybar + ((size_t)t << 11) + lane * 32;
#pragma unroll
    for (int ci = 0; ci < 4; ci++) {
      union { u16 s[8]; u32x4 v; } pk;
#pragma unroll
      for (int j = 0; j < 4; j++) {
        __hip_bfloat162 pr = __float22bfloat162_rn(float2{acc[2 * j][ci], acc[2 * j + 1][ci]});
        *(__hip_bfloat162*)&pk.s[2 * j] = pr;
      }
      *(u32x4*)(op + ci * 8) = pk.v;
    }
  }
}

// ---------------- K3: Out = ybar @ WvoT^T + bout   (M=16384, N=256, K=2048)
__global__ __launch_bounds__(256) void k3(const u16* __restrict__ Yb,
                                          const u16* __restrict__ WvoT,
                                          const float* __restrict__ bout,
                                          float* __restrict__ Out) {
  __shared__ u16 As[128][72];
  __shared__ u16 Bs[128][72];
  int tid = threadIdx.x;
  int wave = tid >> 6, lane = tid & 63;
  int l15 = lane & 15, kg = lane >> 4;
  int m0 = blockIdx.x * 128, n0 = blockIdx.y * 128;
  int sr = tid >> 1, sk = (tid & 1) * 32;
  f32x4 acc[4][4] = {};
#pragma unroll 1
  for (int kc = 0; kc < 2048; kc += 64) {
#pragma unroll
    for (int i = 0; i < 4; i++) {
      *(u32x4*)&As[sr][sk + i * 8] = *(const u32x4*)(Yb + (size_t)(m0 + sr) * 2048 + kc + sk + i * 8);
      *(u32x4*)&Bs[sr][sk + i * 8] = *(const u32x4*)(WvoT + (size_t)(n0 + sr) * 2048 + kc + sk + i * 8);
    }
    __syncthreads();
    int rb = (wave >> 1) * 64, cb = (wave & 1) * 64;
#pragma unroll
    for (int ks = 0; ks < 2; ks++) {
      bf16x8 af[4], bfm[4];
#pragma unroll
      for (int i = 0; i < 4; i++) af[i] = *(const bf16x8*)&As[rb + i * 16 + l15][ks * 32 + kg * 8];
#pragma unroll
      for (int i = 0; i < 4; i++) bfm[i] = *(const bf16x8*)&Bs[cb + i * 16 + l15][ks * 32 + kg * 8];
#pragma unroll
      for (int mt = 0; mt < 4; mt++)
#pragma unroll
        for (int nt = 0; nt < 4; nt++)
          acc[mt][nt] = __builtin_amdgcn_mfma_f32_16x16x32_bf16(af[mt], bfm[nt], acc[mt][nt], 0, 0, 0);
    }
    __syncthreads();
  }
  int rb = m0 + (wave >> 1) * 64, cb = n0 + (wave & 1) * 64;
  int q = lane >> 4;
#pragma unroll
  for (int nt = 0; nt < 4; nt++) {
    float bv = bout[cb + nt * 16 + l15];
#pragma unroll
    for (int mt = 0; mt < 4; mt++)
#pragma unroll
      for (int r = 0; r < 4; r++)
        Out[(size_t)(rb + mt * 16 + q * 4 + r) * 256 + cb + nt * 16 + l15] = acc[mt][nt][r] + bv;
  }
}

extern "C" void kernel_launch(void* const* d_in, const int* in_sizes, int n_in,
                              void* d_out, int out_size, void* d_ws, size_t ws_size,
                              hipStream_t stream) {
  const float* x    = (const float*)d_in[0];
  const float* y    = (const float*)d_in[1];
  const float* Wq   = (const float*)d_in[2];
  const float* Wkv  = (const float*)d_in[3];
  const float* Wout = (const float*)d_in[4];
  const float* bout = (const float*)d_in[5];
  float* out = (float*)d_out;

  char* ws = (char*)d_ws;
  u16* qW   = (u16*)(ws);                          // 16384*2048*2 = 64 MiB
  u16* ybar = (u16*)(ws + ((size_t)64 << 20));     // 64 MiB
  u16* WqkT = (u16*)(ws + ((size_t)128 << 20));    // 2048*256*2 = 1 MiB
  u16* WvoT = (u16*)(ws + ((size_t)129 << 20));    // 256*2048*2 = 1 MiB

  k0a<<<dim3(16, 16), 256, 0, stream>>>(Wq, Wkv, WqkT);
  k0b<<<dim3(16, 16), 256, 0, stream>>>(Wkv, Wout, WvoT);
  k1<<<dim3(128, 16), 256, 0, stream>>>(x, WqkT, qW);
  k2<<<dim3(1024), 64, 0, stream>>>(y, qW, ybar);
  k3<<<dim3(128, 2), 256, 0, stream>>>(ybar, WvoT, bout, out);
}